// Round 8
// baseline (189.623 us; speedup 1.0000x reference)
//
#include <hip/hip_runtime.h>
#include <stdint.h>

#define B_    8192
#define D1_   512
#define D_    256
#define NNEG  100

typedef __attribute__((ext_vector_type(8))) short bf16x8;
typedef __attribute__((ext_vector_type(4))) short bf16x4;
typedef __attribute__((ext_vector_type(4))) float f32x4;

static __device__ __forceinline__ short f2bf(float f) {
  union { float f; unsigned u; } c; c.f = f;
  unsigned r = (c.u + 0x7FFFu + ((c.u >> 16) & 1u)) >> 16;   // RNE
  return (short)r;
}
static __device__ __forceinline__ float bf2f(short s) {
  union { unsigned u; float f; } c; c.u = ((unsigned)(unsigned short)s) << 16;
  return c.f;
}

// ws layout: [0..31] float wsf (0=mse,1=w2,2=aug)  [32..47] int hist[4]
//            [48..51] int ticket   [256..] Wt (256KB)   [+262144..] phi (4MB)

// ---------------- KA: fused  W->Wt(bf16,T) + ||W||^2  +  mse + domain hist ----
// grid 512 x 256 = 131072 threads (== |W|); threads t<8192 also do y/tag work.
__global__ __launch_bounds__(256) void kA_pre(const float* __restrict__ W,
                                              short* __restrict__ Wt,
                                              const float* __restrict__ yp,
                                              const float* __restrict__ yt,
                                              const int* __restrict__ tag,
                                              float* wsf, int* hist) {
  const int t = blockIdx.x * 256 + threadIdx.x;
  const int lane = threadIdx.x & 63, wv = threadIdx.x >> 6;
  __shared__ float lw[4], lm[4];
  __shared__ int lh[4];
  if (threadIdx.x < 4) lh[threadIdx.x] = 0;
  __syncthreads();

  const int k = t >> 8, n = t & 255;
  float w = W[t];
  Wt[n * 512 + k] = f2bf(w);
  float s = w * w;

  float d = 0.f;
  if (t < 8192) {
    d = fabsf(yp[t] - yt[t]);
    atomicAdd(&lh[tag[t]], 1);
  }
  #pragma unroll
  for (int off = 32; off; off >>= 1) {
    s += __shfl_down(s, off);
    d += __shfl_down(d, off);
  }
  if (lane == 0) { lw[wv] = s; lm[wv] = d; }
  __syncthreads();
  if (threadIdx.x == 0) {
    atomicAdd(&wsf[1], lw[0] + lw[1] + lw[2] + lw[3]);
    float dm = lm[0] + lm[1] + lm[2] + lm[3];
    if (dm != 0.f || blockIdx.x < 32) atomicAdd(&wsf[0], dm);
  }
  if (threadIdx.x < 4 && lh[threadIdx.x] != 0)
    atomicAdd(&hist[threadIdx.x], lh[threadIdx.x]);
}

// ---------------- K3: phi = mixup(e1) @ W  (bf16 MFMA, LDS-staged A) ----------
// 512 blocks x 1024 thr (16 waves). Block: 16 rows x all 256 cols.
__global__ __launch_bounds__(1024) void k3_gemm(const float* __restrict__ e1,
                                                const float* __restrict__ lu,
                                                const int* __restrict__ aidx,
                                                const short* __restrict__ Wt,
                                                short* __restrict__ phi) {
  __shared__ short As[16 * 512];            // 16 KB, XOR-swizzled
  char* asb = (char*)As;
  const int t = threadIdx.x;
  const int bm0 = blockIdx.x * 16;

  // --- stage mixed-up A tile (bf16) ---
  {
    const int r = t >> 6;                   // 0..15 (== wave id)
    const int row = bm0 + r;
    const float lmv = 0.9f + 0.1f * lu[row];
    const float omv = 1.f - lmv;
    int an = aidx[row];
    int a2 = an + (an >= row);
    const float* px = e1 + (long)row * D1_;
    const float* py = e1 + (long)a2 * D1_;
    const int c0 = (t & 63) * 4;            // elem col
    #pragma unroll
    for (int j = 0; j < 2; ++j) {
      const int c = c0 + j * 256;
      float4 x = *(const float4*)(px + c);
      float4 y = *(const float4*)(py + c);
      bf16x4 o;
      o[0] = f2bf(lmv * x.x + omv * y.x);
      o[1] = f2bf(lmv * x.y + omv * y.y);
      o[2] = f2bf(lmv * x.z + omv * y.z);
      o[3] = f2bf(lmv * x.w + omv * y.w);
      *(bf16x4*)(asb + r * 1024 + ((c * 2) ^ ((r & 7) << 4))) = o;
    }
  }
  __syncthreads();

  // --- MFMA ---
  const int lane = t & 63, wv = t >> 6;
  const int lo = lane & 15, hi = lane >> 4;
  const short* wb = Wt + (wv * 16 + lo) * 512;

  f32x4 acc = {};
  #pragma unroll
  for (int kk = 0; kk < 16; ++kk) {
    bf16x8 a = *(const bf16x8*)(asb + lo * 1024 + ((kk * 64 + hi * 16) ^ ((lo & 7) << 4)));
    bf16x8 b = *(const bf16x8*)(wb + kk * 32 + hi * 8);
    acc = __builtin_amdgcn_mfma_f32_16x16x32_bf16(a, b, acc, 0, 0, 0);
  }
  // C/D layout: col = lane&15, row = (lane>>4)*4 + q
  #pragma unroll
  for (int q = 0; q < 4; ++q) {
    int R = bm0 + hi * 4 + q;
    phi[R * D_ + wv * 16 + lo] = f2bf(acc[q]);
  }
}

// ---------------- K4: L_aug rows (linearized exp) + fused finalize ------------
// 1 wave per row; half h accumulates negatives i in [h*50, h*50+50).
// Indices pre-staged in LDS with self-exclusion applied; idx prefetch pipelined.
__global__ __launch_bounds__(256) void k4_neg(const short* __restrict__ phi,
                                              const float* __restrict__ e2,
                                              const int* __restrict__ nidx,
                                              float* wsf, int* hist,
                                              int* ticket, float* out) {
  __shared__ int sidx[4 * NNEG];
  __shared__ float lrow[4];
  __shared__ int isLast;

  // stage this block's 400 indices, self-exclusion shift applied
  #pragma unroll
  for (int e = threadIdx.x; e < 4 * NNEG; e += 256) {
    int nn = nidx[blockIdx.x * 4 * NNEG + e];
    int bb = blockIdx.x * 4 + e / NNEG;
    sidx[e] = nn + (nn >= bb);
  }
  __syncthreads();

  const int lane = threadIdx.x & 63;
  const int wv   = threadIdx.x >> 6;
  const int b    = blockIdx.x * 4 + wv;
  const int h    = lane >> 5;              // half owns [h*50, h*50+50)
  const int q    = lane & 31;              // elem chunk q*8 .. q*8+8

  const int base = wv * NNEG + h * 50;
  float acc[8] = {0.f, 0.f, 0.f, 0.f, 0.f, 0.f, 0.f, 0.f};

  int rn[5];
  #pragma unroll
  for (int u = 0; u < 5; ++u) rn[u] = sidx[base + u];

  #pragma unroll 1
  for (int it = 0; it < 10; ++it) {
    bf16x8 v[5];
    #pragma unroll
    for (int u = 0; u < 5; ++u)
      v[u] = *(const bf16x8*)(phi + (long)rn[u] * D_ + q * 8);
    if (it < 9) {
      #pragma unroll
      for (int u = 0; u < 5; ++u) rn[u] = sidx[base + (it + 1) * 5 + u];
    }
    #pragma unroll
    for (int u = 0; u < 5; ++u)
      #pragma unroll
      for (int j = 0; j < 8; ++j)
        acc[j] += bf2f(v[u][j]);
  }

  // dots with e2[b] (neg-sum and positive), then wave reduce
  const float* er = e2 + (long)b * D_ + q * 8;
  float ev[8];
  *(float4*)&ev[0] = *(const float4*)(er);
  *(float4*)&ev[4] = *(const float4*)(er + 4);
  bf16x8 pb = *(const bf16x8*)(phi + (long)b * D_ + q * 8);

  float sneg = 0.f, spos = 0.f;
  #pragma unroll
  for (int j = 0; j < 8; ++j) {
    sneg += acc[j] * ev[j];
    spos += bf2f(pb[j]) * ev[j];
  }
  #pragma unroll
  for (int off = 1; off <= 32; off <<= 1) {
    sneg += __shfl_xor(sneg, off);
    spos += __shfl_xor(spos, off);
  }

  if (lane == 0) {
    spos *= 0.5f;                          // both halves computed the pos dot
    float pos  = 1.f + 1e-6f * spos;
    float negs = 100.f + 1e-6f * sneg;
    lrow[wv] = logf(pos / (1e-6f + pos + negs));
  }
  __syncthreads();

  // one atomic per block, then last-block finalize
  if (threadIdx.x == 0) {
    atomicAdd(&wsf[2], lrow[0] + lrow[1] + lrow[2] + lrow[3]);
    __threadfence();
    int tk = atomicAdd(ticket, 1);
    isLast = (tk == (int)gridDim.x - 1);
  }
  __syncthreads();

  if (isLast && threadIdx.x == 0) {
    __threadfence();
    float augsum = atomicAdd(&wsf[2], 0.f);      // coherent read
    float mse = wsf[0] * (1.f / 8192.f);         // written by earlier kernel
    float reg = 1e-4f * sqrtf(wsf[1]);
    float aug = 0.1f * (-augsum * (1.f / 8192.f));
    // L_supp: S==1.0f bit-exactly in fp32 (tau=1e-10) -> nom=count_diff,
    // den=8192.0f exactly; den+1e-6f rounds to 8192.0f.
    float ss = 0.f;
    for (int t = 0; t < 4; ++t) {
      int c = hist[t];
      int cd = B_ - c;
      if (c > 0 && cd > 0)
        ss += (float)c * logf((float)cd / (8192.f + 1e-6f));
    }
    float supp = 1e-3f * (-ss * (1.f / 8192.f));
    out[0] = mse + reg + aug + supp;
  }
}

extern "C" void kernel_launch(void* const* d_in, const int* in_sizes, int n_in,
                              void* d_out, int out_size, void* d_ws, size_t ws_size,
                              hipStream_t stream) {
  const float* e1  = (const float*)d_in[0];
  const float* e2  = (const float*)d_in[1];
  const float* yp  = (const float*)d_in[2];
  const float* yt  = (const float*)d_in[3];
  const float* W   = (const float*)d_in[4];
  const float* lu  = (const float*)d_in[5];
  const int*   tag = (const int*)d_in[6];
  const int*   aix = (const int*)d_in[7];
  const int*   nix = (const int*)d_in[8];
  float* out = (float*)d_out;

  char* ws     = (char*)d_ws;
  float* wsf   = (float*)ws;                    // [0]=mse [1]=w2 [2]=aug
  int*   hist  = (int*)(ws + 32);               // 4 bins
  int*   ticket= (int*)(ws + 48);
  short* Wt    = (short*)(ws + 256);            // 256x512 bf16 = 256 KB
  short* phi   = (short*)(ws + 256 + 262144);   // 8192x256 bf16 = 4 MB

  hipMemsetAsync(ws, 0, 64, stream);            // zero wsf/hist/ticket
  kA_pre<<<512, 256, 0, stream>>>(W, Wt, yp, yt, tag, wsf, hist);
  k3_gemm<<<512, 1024, 0, stream>>>(e1, lu, aix, Wt, phi);
  k4_neg<<<2048, 256, 0, stream>>>(phi, e2, nix, wsf, hist, ticket, out);
}

// Round 11
// 145.538 us; speedup vs baseline: 1.3029x; 1.3029x over previous
//
#include <hip/hip_runtime.h>
#include <stdint.h>

#define B_    8192
#define D1_   512
#define D_    256
#define NNEG  100

typedef __attribute__((ext_vector_type(8))) short bf16x8;
typedef __attribute__((ext_vector_type(4))) short bf16x4;
typedef __attribute__((ext_vector_type(4))) float f32x4;

static __device__ __forceinline__ short f2bf(float f) {
  union { float f; unsigned u; } c; c.f = f;
  unsigned r = (c.u + 0x7FFFu + ((c.u >> 16) & 1u)) >> 16;   // RNE
  return (short)r;
}
static __device__ __forceinline__ float bf2f(short s) {
  union { unsigned u; float f; } c; c.u = ((unsigned)(unsigned short)s) << 16;
  return c.f;
}

// ws layout: [0..31] float wsf (0=mse,1=w2,2=aug)  [32..47] int hist[4]
//            [256..] Wt (256KB)   [+262144..] phi (4MB)

// ---------------- KA: fused  W->Wt(bf16,T) + ||W||^2  +  mse + domain hist ----
__global__ __launch_bounds__(256) void kA_pre(const float* __restrict__ W,
                                              short* __restrict__ Wt,
                                              const float* __restrict__ yp,
                                              const float* __restrict__ yt,
                                              const int* __restrict__ tag,
                                              float* wsf, int* hist) {
  const int t = blockIdx.x * 256 + threadIdx.x;
  const int lane = threadIdx.x & 63, wv = threadIdx.x >> 6;
  __shared__ float lw[4], lm[4];
  __shared__ int lh[4];
  if (threadIdx.x < 4) lh[threadIdx.x] = 0;
  __syncthreads();

  const int k = t >> 8, n = t & 255;
  float w = W[t];
  Wt[n * 512 + k] = f2bf(w);
  float s = w * w;

  float d = 0.f;
  if (t < 8192) {
    d = fabsf(yp[t] - yt[t]);
    atomicAdd(&lh[tag[t]], 1);
  }
  #pragma unroll
  for (int off = 32; off; off >>= 1) {
    s += __shfl_down(s, off);
    d += __shfl_down(d, off);
  }
  if (lane == 0) { lw[wv] = s; lm[wv] = d; }
  __syncthreads();
  if (threadIdx.x == 0) {
    atomicAdd(&wsf[1], lw[0] + lw[1] + lw[2] + lw[3]);
    float dm = lm[0] + lm[1] + lm[2] + lm[3];
    if (dm != 0.f || blockIdx.x < 32) atomicAdd(&wsf[0], dm);
  }
  if (threadIdx.x < 4 && lh[threadIdx.x] != 0)
    atomicAdd(&hist[threadIdx.x], lh[threadIdx.x]);
}

// ---------------- K3: phi = mixup(e1) @ W  (bf16 MFMA, LDS-staged A) ----------
__global__ __launch_bounds__(1024) void k3_gemm(const float* __restrict__ e1,
                                                const float* __restrict__ lu,
                                                const int* __restrict__ aidx,
                                                const short* __restrict__ Wt,
                                                short* __restrict__ phi) {
  __shared__ short As[16 * 512];            // 16 KB, XOR-swizzled
  char* asb = (char*)As;
  const int t = threadIdx.x;
  const int bm0 = blockIdx.x * 16;

  {
    const int r = t >> 6;                   // 0..15
    const int row = bm0 + r;
    const float lmv = 0.9f + 0.1f * lu[row];
    const float omv = 1.f - lmv;
    int an = aidx[row];
    int a2 = an + (an >= row);
    const float* px = e1 + (long)row * D1_;
    const float* py = e1 + (long)a2 * D1_;
    const int c0 = (t & 63) * 4;
    #pragma unroll
    for (int j = 0; j < 2; ++j) {
      const int c = c0 + j * 256;
      float4 x = *(const float4*)(px + c);
      float4 y = *(const float4*)(py + c);
      bf16x4 o;
      o[0] = f2bf(lmv * x.x + omv * y.x);
      o[1] = f2bf(lmv * x.y + omv * y.y);
      o[2] = f2bf(lmv * x.z + omv * y.z);
      o[3] = f2bf(lmv * x.w + omv * y.w);
      *(bf16x4*)(asb + r * 1024 + ((c * 2) ^ ((r & 7) << 4))) = o;
    }
  }
  __syncthreads();

  const int lane = t & 63, wv = t >> 6;
  const int lo = lane & 15, hi = lane >> 4;
  const short* wb = Wt + (wv * 16 + lo) * 512;

  f32x4 acc = {};
  #pragma unroll
  for (int kk = 0; kk < 16; ++kk) {
    bf16x8 a = *(const bf16x8*)(asb + lo * 1024 + ((kk * 64 + hi * 16) ^ ((lo & 7) << 4)));
    bf16x8 b = *(const bf16x8*)(wb + kk * 32 + hi * 8);
    acc = __builtin_amdgcn_mfma_f32_16x16x32_bf16(a, b, acc, 0, 0, 0);
  }
  #pragma unroll
  for (int q = 0; q < 4; ++q) {
    int R = bm0 + hi * 4 + q;
    phi[R * D_ + wv * 16 + lo] = f2bf(acc[q]);
  }
}

// ---------------- K4: L_aug rows, linearized exp, 2-deep pipelined gather -----
// 1 wave/row; half h owns negatives i = 2k+h (same order as the bit-exact R2
// measurement). Ping-pong register batches: batch it+1's 5 gathers in flight
// while batch it accumulates -> counted vmcnt, no per-iter drain.
static __device__ __forceinline__ void load5(const int2* __restrict__ nrow2,
                                             int basePair, int b, int h, int q,
                                             const short* __restrict__ phi,
                                             int* r, bf16x8* v) {
  #pragma unroll
  for (int u = 0; u < 5; ++u) {
    int2 p = nrow2[basePair + u];
    int nn = h ? p.y : p.x;
    r[u] = nn + (nn >= b);
  }
  #pragma unroll
  for (int u = 0; u < 5; ++u)
    v[u] = *(const bf16x8*)(phi + (long)r[u] * D_ + q * 8);
}

static __device__ __forceinline__ void acc5(const bf16x8* v, float* acc) {
  #pragma unroll
  for (int u = 0; u < 5; ++u)
    #pragma unroll
    for (int j = 0; j < 8; ++j)
      acc[j] += bf2f(v[u][j]);
}

__global__ __launch_bounds__(256) void k4_neg(const short* __restrict__ phi,
                                              const float* __restrict__ e2,
                                              const int* __restrict__ nidx,
                                              float* wsf) {
  const int lane = threadIdx.x & 63;
  const int wv   = threadIdx.x >> 6;
  const int b    = blockIdx.x * 4 + wv;
  const int h    = lane >> 5;              // half: even/odd negatives
  const int q    = lane & 31;              // elem chunk q*8 .. q*8+8

  const int2* nrow2 = (const int2*)(nidx + b * NNEG);   // 50 even/odd pairs
  float acc[8] = {0.f, 0.f, 0.f, 0.f, 0.f, 0.f, 0.f, 0.f};

  int ra[5], rb[5];
  bf16x8 va[5], vb[5];

  load5(nrow2,  0, b, h, q, phi, ra, va);
  load5(nrow2,  5, b, h, q, phi, rb, vb);
  acc5(va, acc); load5(nrow2, 10, b, h, q, phi, ra, va);
  acc5(vb, acc); load5(nrow2, 15, b, h, q, phi, rb, vb);
  acc5(va, acc); load5(nrow2, 20, b, h, q, phi, ra, va);
  acc5(vb, acc); load5(nrow2, 25, b, h, q, phi, rb, vb);
  acc5(va, acc); load5(nrow2, 30, b, h, q, phi, ra, va);
  acc5(vb, acc); load5(nrow2, 35, b, h, q, phi, rb, vb);
  acc5(va, acc); load5(nrow2, 40, b, h, q, phi, ra, va);
  acc5(vb, acc); load5(nrow2, 45, b, h, q, phi, rb, vb);
  acc5(va, acc);
  acc5(vb, acc);

  // dots with e2[b] (neg-sum and positive), then wave reduce
  const float* er = e2 + (long)b * D_ + q * 8;
  float ev[8];
  *(float4*)&ev[0] = *(const float4*)(er);
  *(float4*)&ev[4] = *(const float4*)(er + 4);
  bf16x8 pb = *(const bf16x8*)(phi + (long)b * D_ + q * 8);

  float sneg = 0.f, spos = 0.f;
  #pragma unroll
  for (int j = 0; j < 8; ++j) {
    sneg += acc[j] * ev[j];
    spos += bf2f(pb[j]) * ev[j];
  }
  #pragma unroll
  for (int off = 1; off <= 32; off <<= 1) {
    sneg += __shfl_xor(sneg, off);
    spos += __shfl_xor(spos, off);
  }

  __shared__ float lrow[4];
  if (lane == 0) {
    spos *= 0.5f;                          // both halves computed the pos dot
    float pos  = 1.f + 1e-6f * spos;
    float negs = 100.f + 1e-6f * sneg;
    lrow[wv] = logf(pos / (1e-6f + pos + negs));
  }
  __syncthreads();
  if (threadIdx.x == 0)
    atomicAdd(&wsf[2], lrow[0] + lrow[1] + lrow[2] + lrow[3]);
}

// ---------------- K5: combine ----------------
__global__ void k5_fin(const float* wsf, const int* hist, float* out) {
  if (threadIdx.x == 0 && blockIdx.x == 0) {
    float mse = wsf[0] * (1.f / 8192.f);
    float reg = 1e-4f * sqrtf(wsf[1]);
    float aug = 0.1f * (-wsf[2] * (1.f / 8192.f));
    // L_supp: S==1.0f bit-exactly in fp32 (tau=1e-10) -> nom=count_diff,
    // den=8192.0f exactly; den+1e-6f rounds to 8192.0f.
    float ss = 0.f;
    for (int t = 0; t < 4; ++t) {
      int c = hist[t];
      int cd = B_ - c;
      if (c > 0 && cd > 0)
        ss += (float)c * logf((float)cd / (8192.f + 1e-6f));
    }
    float supp = 1e-3f * (-ss * (1.f / 8192.f));
    out[0] = mse + reg + aug + supp;
  }
}

extern "C" void kernel_launch(void* const* d_in, const int* in_sizes, int n_in,
                              void* d_out, int out_size, void* d_ws, size_t ws_size,
                              hipStream_t stream) {
  const float* e1  = (const float*)d_in[0];
  const float* e2  = (const float*)d_in[1];
  const float* yp  = (const float*)d_in[2];
  const float* yt  = (const float*)d_in[3];
  const float* W   = (const float*)d_in[4];
  const float* lu  = (const float*)d_in[5];
  const int*   tag = (const int*)d_in[6];
  const int*   aix = (const int*)d_in[7];
  const int*   nix = (const int*)d_in[8];
  float* out = (float*)d_out;

  char* ws    = (char*)d_ws;
  float* wsf  = (float*)ws;                     // [0]=mse [1]=w2 [2]=aug
  int*   hist = (int*)(ws + 32);                // 4 bins
  short* Wt   = (short*)(ws + 256);             // 256x512 bf16 = 256 KB
  short* phi  = (short*)(ws + 256 + 262144);    // 8192x256 bf16 = 4 MB

  hipMemsetAsync(ws, 0, 64, stream);            // zero wsf/hist
  kA_pre<<<512, 256, 0, stream>>>(W, Wt, yp, yt, tag, wsf, hist);
  k3_gemm<<<512, 1024, 0, stream>>>(e1, lu, aix, Wt, phi);
  k4_neg<<<2048, 256, 0, stream>>>(phi, e2, nix, wsf);
  k5_fin<<<1, 64, 0, stream>>>(wsf, hist, out);
}

// Round 13
// 145.110 us; speedup vs baseline: 1.3068x; 1.0029x over previous
//
#include <hip/hip_runtime.h>
#include <stdint.h>

#define B_    8192
#define D1_   512
#define D_    256
#define NNEG  100

typedef __attribute__((ext_vector_type(8))) short bf16x8;
typedef __attribute__((ext_vector_type(4))) short bf16x4;
typedef __attribute__((ext_vector_type(4))) float f32x4;
typedef __attribute__((ext_vector_type(2))) float f32x2;
typedef __attribute__((ext_vector_type(2))) unsigned int u32x2;

static __device__ __forceinline__ short f2bf(float f) {
  union { float f; unsigned u; } c; c.f = f;
  unsigned r = (c.u + 0x7FFFu + ((c.u >> 16) & 1u)) >> 16;   // RNE
  return (short)r;
}

// ws layout: [0..31] float wsf (0=mse,1=w2,2=aug)  [32..47] int hist[4]
//            [256..] Wt (256KB)   [+262144..] phi8 (2MB, fp8 e4m3)

// ---------------- KA: fused  W->Wt(bf16,T) + ||W||^2  +  mse + domain hist ----
__global__ __launch_bounds__(256) void kA_pre(const float* __restrict__ W,
                                              short* __restrict__ Wt,
                                              const float* __restrict__ yp,
                                              const float* __restrict__ yt,
                                              const int* __restrict__ tag,
                                              float* wsf, int* hist) {
  const int t = blockIdx.x * 256 + threadIdx.x;
  const int lane = threadIdx.x & 63, wv = threadIdx.x >> 6;
  __shared__ float lw[4], lm[4];
  __shared__ int lh[4];
  if (threadIdx.x < 4) lh[threadIdx.x] = 0;
  __syncthreads();

  const int k = t >> 8, n = t & 255;
  float w = W[t];
  Wt[n * 512 + k] = f2bf(w);
  float s = w * w;

  float d = 0.f;
  if (t < 8192) {
    d = fabsf(yp[t] - yt[t]);
    atomicAdd(&lh[tag[t]], 1);
  }
  #pragma unroll
  for (int off = 32; off; off >>= 1) {
    s += __shfl_down(s, off);
    d += __shfl_down(d, off);
  }
  if (lane == 0) { lw[wv] = s; lm[wv] = d; }
  __syncthreads();
  if (threadIdx.x == 0) {
    atomicAdd(&wsf[1], lw[0] + lw[1] + lw[2] + lw[3]);
    float dm = lm[0] + lm[1] + lm[2] + lm[3];
    if (dm != 0.f || blockIdx.x < 32) atomicAdd(&wsf[0], dm);
  }
  if (threadIdx.x < 4 && lh[threadIdx.x] != 0)
    atomicAdd(&hist[threadIdx.x], lh[threadIdx.x]);
}

// ---------------- K3: phi = mixup(e1) @ W  (bf16 MFMA, fp8 output) -----------
__global__ __launch_bounds__(1024) void k3_gemm(const float* __restrict__ e1,
                                                const float* __restrict__ lu,
                                                const int* __restrict__ aidx,
                                                const short* __restrict__ Wt,
                                                unsigned char* __restrict__ phi8) {
  __shared__ short As[16 * 512];            // 16 KB, XOR-swizzled
  char* asb = (char*)As;
  const int t = threadIdx.x;
  const int bm0 = blockIdx.x * 16;

  {
    const int r = t >> 6;                   // 0..15
    const int row = bm0 + r;
    const float lmv = 0.9f + 0.1f * lu[row];
    const float omv = 1.f - lmv;
    int an = aidx[row];
    int a2 = an + (an >= row);
    const float* px = e1 + (long)row * D1_;
    const float* py = e1 + (long)a2 * D1_;
    const int c0 = (t & 63) * 4;
    #pragma unroll
    for (int j = 0; j < 2; ++j) {
      const int c = c0 + j * 256;
      float4 x = *(const float4*)(px + c);
      float4 y = *(const float4*)(py + c);
      bf16x4 o;
      o[0] = f2bf(lmv * x.x + omv * y.x);
      o[1] = f2bf(lmv * x.y + omv * y.y);
      o[2] = f2bf(lmv * x.z + omv * y.z);
      o[3] = f2bf(lmv * x.w + omv * y.w);
      *(bf16x4*)(asb + r * 1024 + ((c * 2) ^ ((r & 7) << 4))) = o;
    }
  }
  __syncthreads();

  const int lane = t & 63, wv = t >> 6;
  const int lo = lane & 15, hi = lane >> 4;
  const short* wb = Wt + (wv * 16 + lo) * 512;

  f32x4 acc = {};
  #pragma unroll
  for (int kk = 0; kk < 16; ++kk) {
    bf16x8 a = *(const bf16x8*)(asb + lo * 1024 + ((kk * 64 + hi * 16) ^ ((lo & 7) << 4)));
    bf16x8 b = *(const bf16x8*)(wb + kk * 32 + hi * 8);
    acc = __builtin_amdgcn_mfma_f32_16x16x32_bf16(a, b, acc, 0, 0, 0);
  }
  // C/D layout: col = lane&15, row = (lane>>4)*4 + q
  #pragma unroll
  for (int q = 0; q < 4; ++q) {
    int R = bm0 + hi * 4 + q;
    int pk = __builtin_amdgcn_cvt_pk_fp8_f32(acc[q], acc[q], 0, false);
    phi8[R * D_ + wv * 16 + lo] = (unsigned char)(pk & 0xFF);
  }
}

// ---------------- K4: L_aug rows, linearized exp, fp8 gather, 2-deep pipe -----
// 1 wave/row; half h owns negatives i = 2k+h. Ping-pong register batches keep
// 10 gathered rows in flight; HW v_cvt_pk_f32_fp8 unpacks 2 elems/op.
static __device__ __forceinline__ void load5f8(const int2* __restrict__ nrow2,
                                               int basePair, int b, int h, int q,
                                               const unsigned char* __restrict__ phi8,
                                               u32x2* v) {
  int r[5];
  #pragma unroll
  for (int u = 0; u < 5; ++u) {
    int2 p = nrow2[basePair + u];
    int nn = h ? p.y : p.x;
    r[u] = nn + (nn >= b);
  }
  #pragma unroll
  for (int u = 0; u < 5; ++u)
    v[u] = *(const u32x2*)(phi8 + (long)r[u] * D_ + q * 8);
}

static __device__ __forceinline__ void acc5f8(const u32x2* v, float* acc) {
  #pragma unroll
  for (int u = 0; u < 5; ++u) {
    f32x2 a0 = __builtin_amdgcn_cvt_pk_f32_fp8((int)v[u][0], false);
    f32x2 a1 = __builtin_amdgcn_cvt_pk_f32_fp8((int)v[u][0], true);
    f32x2 a2 = __builtin_amdgcn_cvt_pk_f32_fp8((int)v[u][1], false);
    f32x2 a3 = __builtin_amdgcn_cvt_pk_f32_fp8((int)v[u][1], true);
    acc[0] += a0[0]; acc[1] += a0[1];
    acc[2] += a1[0]; acc[3] += a1[1];
    acc[4] += a2[0]; acc[5] += a2[1];
    acc[6] += a3[0]; acc[7] += a3[1];
  }
}

__global__ __launch_bounds__(256) void k4_neg(const unsigned char* __restrict__ phi8,
                                              const float* __restrict__ e2,
                                              const int* __restrict__ nidx,
                                              float* wsf) {
  const int lane = threadIdx.x & 63;
  const int wv   = threadIdx.x >> 6;
  const int b    = blockIdx.x * 4 + wv;
  const int h    = lane >> 5;              // half: even/odd negatives
  const int q    = lane & 31;              // elem chunk q*8 .. q*8+8

  const int2* nrow2 = (const int2*)(nidx + b * NNEG);   // 50 even/odd pairs
  float acc[8] = {0.f, 0.f, 0.f, 0.f, 0.f, 0.f, 0.f, 0.f};

  u32x2 va[5], vb[5];

  load5f8(nrow2,  0, b, h, q, phi8, va);
  load5f8(nrow2,  5, b, h, q, phi8, vb);
  acc5f8(va, acc); load5f8(nrow2, 10, b, h, q, phi8, va);
  acc5f8(vb, acc); load5f8(nrow2, 15, b, h, q, phi8, vb);
  acc5f8(va, acc); load5f8(nrow2, 20, b, h, q, phi8, va);
  acc5f8(vb, acc); load5f8(nrow2, 25, b, h, q, phi8, vb);
  acc5f8(va, acc); load5f8(nrow2, 30, b, h, q, phi8, va);
  acc5f8(vb, acc); load5f8(nrow2, 35, b, h, q, phi8, vb);
  acc5f8(va, acc); load5f8(nrow2, 40, b, h, q, phi8, va);
  acc5f8(vb, acc); load5f8(nrow2, 45, b, h, q, phi8, vb);
  acc5f8(va, acc);
  acc5f8(vb, acc);

  // dots with e2[b] (neg-sum and positive), then wave reduce
  const float* er = e2 + (long)b * D_ + q * 8;
  float ev[8];
  *(float4*)&ev[0] = *(const float4*)(er);
  *(float4*)&ev[4] = *(const float4*)(er + 4);
  u32x2 pw = *(const u32x2*)(phi8 + (long)b * D_ + q * 8);
  f32x2 p0 = __builtin_amdgcn_cvt_pk_f32_fp8((int)pw[0], false);
  f32x2 p1 = __builtin_amdgcn_cvt_pk_f32_fp8((int)pw[0], true);
  f32x2 p2 = __builtin_amdgcn_cvt_pk_f32_fp8((int)pw[1], false);
  f32x2 p3 = __builtin_amdgcn_cvt_pk_f32_fp8((int)pw[1], true);
  float pv[8] = {p0[0], p0[1], p1[0], p1[1], p2[0], p2[1], p3[0], p3[1]};

  float sneg = 0.f, spos = 0.f;
  #pragma unroll
  for (int j = 0; j < 8; ++j) {
    sneg += acc[j] * ev[j];
    spos += pv[j] * ev[j];
  }
  #pragma unroll
  for (int off = 1; off <= 32; off <<= 1) {
    sneg += __shfl_xor(sneg, off);
    spos += __shfl_xor(spos, off);
  }

  __shared__ float lrow[4];
  if (lane == 0) {
    spos *= 0.5f;                          // both halves computed the pos dot
    float pos  = 1.f + 1e-6f * spos;
    float negs = 100.f + 1e-6f * sneg;
    lrow[wv] = logf(pos / (1e-6f + pos + negs));
  }
  __syncthreads();
  if (threadIdx.x == 0)
    atomicAdd(&wsf[2], lrow[0] + lrow[1] + lrow[2] + lrow[3]);
}

// ---------------- K5: combine ----------------
__global__ void k5_fin(const float* wsf, const int* hist, float* out) {
  if (threadIdx.x == 0 && blockIdx.x == 0) {
    float mse = wsf[0] * (1.f / 8192.f);
    float reg = 1e-4f * sqrtf(wsf[1]);
    float aug = 0.1f * (-wsf[2] * (1.f / 8192.f));
    // L_supp: S==1.0f bit-exactly in fp32 (tau=1e-10) -> nom=count_diff,
    // den=8192.0f exactly; den+1e-6f rounds to 8192.0f.
    float ss = 0.f;
    for (int t = 0; t < 4; ++t) {
      int c = hist[t];
      int cd = B_ - c;
      if (c > 0 && cd > 0)
        ss += (float)c * logf((float)cd / (8192.f + 1e-6f));
    }
    float supp = 1e-3f * (-ss * (1.f / 8192.f));
    out[0] = mse + reg + aug + supp;
  }
}

extern "C" void kernel_launch(void* const* d_in, const int* in_sizes, int n_in,
                              void* d_out, int out_size, void* d_ws, size_t ws_size,
                              hipStream_t stream) {
  const float* e1  = (const float*)d_in[0];
  const float* e2  = (const float*)d_in[1];
  const float* yp  = (const float*)d_in[2];
  const float* yt  = (const float*)d_in[3];
  const float* W   = (const float*)d_in[4];
  const float* lu  = (const float*)d_in[5];
  const int*   tag = (const int*)d_in[6];
  const int*   aix = (const int*)d_in[7];
  const int*   nix = (const int*)d_in[8];
  float* out = (float*)d_out;

  char* ws    = (char*)d_ws;
  float* wsf  = (float*)ws;                     // [0]=mse [1]=w2 [2]=aug
  int*   hist = (int*)(ws + 32);                // 4 bins
  short* Wt   = (short*)(ws + 256);             // 256x512 bf16 = 256 KB
  unsigned char* phi8 = (unsigned char*)(ws + 256 + 262144);  // 8192x256 fp8 = 2 MB

  hipMemsetAsync(ws, 0, 64, stream);            // zero wsf/hist
  kA_pre<<<512, 256, 0, stream>>>(W, Wt, yp, yt, tag, wsf, hist);
  k3_gemm<<<512, 1024, 0, stream>>>(e1, lu, aix, Wt, phi8);
  k4_neg<<<2048, 256, 0, stream>>>(phi8, e2, nix, wsf);
  k5_fin<<<1, 64, 0, stream>>>(wsf, hist, out);
}